// Round 16
// baseline (61.277 us; speedup 1.0000x reference)
//
#include <hip/hip_runtime.h>

constexpr int Bn = 65536;   // rows (entity pairs)
constexpr int Cn = 512;     // relation classes

#define L2E 1.4426950408889634f
#define LN2 0.6931471805599453f

typedef float f32x4 __attribute__((ext_vector_type(4)));

// Global->LDS DMA: no VGPR destination, so the register allocator cannot
// serialize the pipeline. HW writes lane l's 16B to ldsbase + l*16.
__device__ __forceinline__ void gl2lds16(const float* g, float* l) {
  __builtin_amdgcn_global_load_lds(
      (const __attribute__((address_space(1))) void*)g,
      (__attribute__((address_space(3))) void*)l, 16, 0, 0);
}

__device__ __forceinline__ uint32_t lds_addr(const void* p) {
  return (uint32_t)(uintptr_t)(__attribute__((address_space(3))) const char*)(const char*)p;
}

// DPP lane-shuffle on the VALU pipe (zero DS-pipe traffic).
template <int Ctrl, int RowMask>
__device__ __forceinline__ float dpp_get(float x, float ident) {
  return __int_as_float(__builtin_amdgcn_update_dpp(
      __float_as_int(ident), __float_as_int(x), Ctrl, RowMask, 0xf, false));
}

// Depth-4 probe at constant everything-else vs R11: same 64KB LDS/block,
// same 512x256 grid (8 waves/CU, 2/SIMD), same 4KB-per-row layout -- but
// FOUR 4KB slots per wave (1 row each) instead of two 8KB slots. Steady
// state vmcnt(12): 3 rows (12-16KB) continuously in flight per wave vs
// R11's bursty 8KB-then-sleep. Tests whether continuous queue depth (not
// burst size) is what the TA/L2 service path rewards.
__global__ __launch_bounds__(256, 2) void matloss_main(
    const float* __restrict__ logits,
    const float* __restrict__ labels,
    double* __restrict__ acc) {

  const int lane = threadIdx.x & 63;
  const int wib  = threadIdx.x >> 6;
  const int gw   = blockIdx.x * 4 + wib;        // 2048 waves, all resident
  constexpr int NW = 2048;                      // row stride
  constexpr int IT = 32;                        // iterations (1 row each)

  __shared__ float smem[4 * 4 * 1024];          // 64KB: [wave][slot4][1024 f32]
  float* base = &smem[wib * 4096];              // 4 slots x 4KB per wave

  auto stage = [&](int i) {                     // 4 vmem ops, 4KB, zero VGPRs
    const size_t row = (size_t)(gw + i * NW);
    const float* gl = logits + row * Cn + lane * 4;
    const float* gb = labels + row * Cn + lane * 4;
    float* s = base + (i & 3) * 1024;           // slot: lg[512] then lb[512]
    gl2lds16(gl,       s);
    gl2lds16(gl + 256, s + 256);
    gl2lds16(gb,       s + 512);
    gl2lds16(gb + 256, s + 768);
  };

  stage(0); stage(1); stage(2); stage(3);       // prologue: 16 loads in flight

  const uint32_t abase = lds_addr(base) + lane * 16;

  float a_term = 0.f, a_cnt = 0.f, a_l2 = 0.f;

#pragma unroll
  for (int i = 0; i < IT; ++i) {
    // wait for slot (i&3): refills run through i=27, so outstanding before
    // the wait is 16 until i=28, then 12/8/4.
    if      (i < 28)  asm volatile("s_waitcnt vmcnt(12)" ::: "memory");
    else if (i == 28) asm volatile("s_waitcnt vmcnt(12)" ::: "memory");
    else if (i == 29) asm volatile("s_waitcnt vmcnt(8)"  ::: "memory");
    else if (i == 30) asm volatile("s_waitcnt vmcnt(4)"  ::: "memory");
    else              asm volatile("s_waitcnt vmcnt(0)"  ::: "memory");
    __builtin_amdgcn_sched_barrier(0);

    f32x4 xa, xb, la, lc;
    const uint32_t va = abase + (i & 3) * 4096;
    asm volatile("ds_read_b128 %0, %4\n\t"
                 "ds_read_b128 %1, %4 offset:1024\n\t"
                 "ds_read_b128 %2, %4 offset:2048\n\t"
                 "ds_read_b128 %3, %4 offset:3072"
                 : "=&v"(xa), "=&v"(xb), "=&v"(la), "=&v"(lc)
                 : "v"(va));
    asm volatile("s_waitcnt lgkmcnt(0)" ::: "memory");
    __builtin_amdgcn_sched_barrier(0);          // rule #18: no consumer hoisting

    if (i + 4 < IT) stage(i + 4);               // refill freed slot under compute

    float x[8] = {xa.x, xa.y, xa.z, xa.w, xb.x, xb.y, xb.z, xb.w};
    float l[8] = {la.x, la.y, la.z, la.w, lc.x, lc.y, lc.z, lc.w};
    float xz = __int_as_float(__builtin_amdgcn_readfirstlane(__float_as_int(x[0])));
    if (lane == 0) l[0] = 0.f;                  // threshold class: label forced 0

    // P  = prod over positives of (1 + exp(-|x|));  PM = sum pos min(x,0)
    // S  = sum over negatives of exp(x)  (no-max LSE: |x| < ~6)
    float P = 1.f, S = 0.f, PM = 0.f, CN = 0.f;
#pragma unroll
    for (int k = 0; k < 8; ++k) {
      bool  pos = (l[k] != 0.f);
      float sel = pos ? -fabsf(x[k]) : x[k];
      float e   = __builtin_amdgcn_exp2f(sel * L2E);
      P  *= fmaf(l[k], e, 1.f);
      S  += pos ? 0.f : e;
      PM  = fmaf(l[k], fminf(x[k], 0.f), PM);
      CN += l[k];
    }

    // wave64 reduce on VALU pipe (4 independent chains)
#define RED4(CTRL, RM)                      \
    S  += dpp_get<CTRL, RM>(S,  0.f);       \
    CN += dpp_get<CTRL, RM>(CN, 0.f);       \
    PM += dpp_get<CTRL, RM>(PM, 0.f);       \
    P  *= dpp_get<CTRL, RM>(P,  1.f);
    RED4(0x111, 0xf)                        // row_shr:1
    RED4(0x112, 0xf)                        // row_shr:2
    RED4(0x114, 0xf)                        // row_shr:4
    RED4(0x118, 0xf)                        // row_shr:8
    RED4(0x142, 0xa)                        // row_bcast:15 (rows 1,3)
    RED4(0x143, 0xc)                        // row_bcast:31 (rows 2,3)
#undef RED4
    float Sw  = __int_as_float(__builtin_amdgcn_readlane(__float_as_int(S),  63));
    float CNw = __int_as_float(__builtin_amdgcn_readlane(__float_as_int(CN), 63));
    float PMw = __int_as_float(__builtin_amdgcn_readlane(__float_as_int(PM), 63));
    float Pw  = __int_as_float(__builtin_amdgcn_readlane(__float_as_int(P),  63));

    a_l2 += LN2 * __builtin_amdgcn_logf(Sw) - xz;   // lse - x0
    if (CNw > 0.f) {                          // wave-uniform branch
      float t0  = __builtin_amdgcn_exp2f(-fabsf(xz) * L2E);
      float ls0 = fminf(-xz, 0.f) - LN2 * __builtin_amdgcn_logf(1.f + t0);
      a_term += ls0 + PMw - LN2 * __builtin_amdgcn_logf(Pw);
      a_cnt  += 1.f + CNw;
    }
  }

  // block reduce: reuse staging LDS (all staging reads done; barrier first)
  __syncthreads();
  if (lane == 0) { smem[wib] = a_term; smem[4 + wib] = a_cnt; smem[8 + wib] = a_l2; }
  __syncthreads();
  if (threadIdx.x == 0) {
    atomicAdd(&acc[0], (double)(smem[0] + smem[1] + smem[2]  + smem[3]));
    atomicAdd(&acc[1], (double)(smem[4] + smem[5] + smem[6]  + smem[7]));
    atomicAdd(&acc[2], (double)(smem[8] + smem[9] + smem[10] + smem[11]));
  }
}

__global__ void matloss_final(const double* __restrict__ acc, float* __restrict__ out) {
  out[0] = (float)(-acc[0] / acc[1] + acc[2] / (double)Bn);
}

extern "C" void kernel_launch(void* const* d_in, const int* in_sizes, int n_in,
                              void* d_out, int out_size, void* d_ws, size_t ws_size,
                              hipStream_t stream) {
  const float* logits = (const float*)d_in[0];
  const float* labels = (const float*)d_in[1];
  float* out = (float*)d_out;
  double* acc = (double*)d_ws;

  hipMemsetAsync(d_ws, 0, 3 * sizeof(double), stream);  // zero accumulators (capture-safe)
  matloss_main<<<512, 256, 0, stream>>>(logits, labels, acc);
  matloss_final<<<1, 1, 0, stream>>>(acc, out);
}